// Round 5
// baseline (24.792 us; speedup 1.0000x reference)
//
#include <hip/hip_runtime.h>
#include <math.h>
#include <stdint.h>

// Problem constants (fixed by the reference)
constexpr int NQ    = 33;        // N+1
constexpr int NQP   = 34;        // padded leading dim
constexpr int NSQ   = NQ * NQ;   // 1089
constexpr int NN    = 32;        // N
constexpr int ITERS = 10;        // sinkhorn iterations
constexpr int BLK   = 1024;

// relu(nw[triu_index(a,b)]) for node labels a,b in [0,8); 0 on diagonal.
__device__ __forceinline__ float node_cost(int a, int b, const float* __restrict__ nw) {
    if (a == b) return 0.f;
    int lo = min(a, b), hi = max(a, b);
    return fmaxf(nw[lo * (15 - lo) / 2 + hi - lo - 1], 0.f);
}

// One block per pair. ged[p] -> ged_ws.
__global__ __launch_bounds__(BLK, 1) void ged_kernel(
    const float* __restrict__ nw, const float* __restrict__ ew,
    const int* __restrict__ A, const int* __restrict__ labels,
    const int* __restrict__ pairs, float* __restrict__ ged_ws)
{
    __shared__ float S[NQ][NQP];             // S0, scaled in place to final V
    __shared__ float H[5][NQ][NQP];          // H[x][i][k] = sum_l f(x,A2[k,l]) V[i,l]
    __shared__ unsigned char A1s[NQ][36];    // padded rows, word-readable
    __shared__ unsigned char A2s[NQ][36];
    __shared__ float ncost_s[8][8];
    __shared__ float rr[NQ], cc[NQ];
    __shared__ float wredq[BLK/64], wredl[BLK/64];

    const int t  = threadIdx.x;
    const int p  = blockIdx.x;
    const int g1 = pairs[2*p+0], g2 = pairs[2*p+1];

    // uniform scalars (scalar loads; same for every thread)
    const float e01 = fmaxf(ew[0], 0.f), e02 = fmaxf(ew[1], 0.f), e03 = fmaxf(ew[2], 0.f);
    const float e12 = fmaxf(ew[3], 0.f), e13 = fmaxf(ew[4], 0.f), e23 = fmaxf(ew[5], 0.f);
    const float EID = fmaxf(ew[6], 0.f);
    const float NID = fmaxf(nw[28], 0.f);
    const float ENID = __expf(-0.5f * NID);

    const int wid = t >> 6;
    if (wid == 0) {
        // ================= wave 0: fully in-register sinkhorn =================
        // Lane L<32: row/col id, elements 0..16.  Lane L>=32: id=L-32, elements 17..32
        // (element 32 is the ENID border, coefficient 1.0 supplied by lane 63's
        //  r/c copy forced to 1.0; lane 31 keeps the true copy of r31/c31).
        const int lane = t;
        const int half = lane >> 5;
        const int id   = lane & 31;
        const int l1_self = labels[g1*NN + id];
        const int l2_self = labels[g2*NN + id];

        float sreg[17], treg[17];
        int   idxr[17];
        #pragma unroll
        for (int m = 0; m < 17; ++m) {
            int hs = 17 + m;
            int src = half ? ((hs <= 31) ? hs : 63) : m;
            idxr[m] = src << 2;
        }
        #pragma unroll
        for (int m = 0; m < 15; ++m) {
            int j = half * 17 + m;                 // 0..14 or 17..31
            sreg[m] = __expf(-0.5f * node_cost(l1_self, labels[g2*NN + j], nw));
            treg[m] = __expf(-0.5f * node_cost(labels[g1*NN + j], l2_self, nw));
        }
        if (!half) {
            sreg[15] = __expf(-0.5f * node_cost(l1_self, labels[g2*NN + 15], nw));
            treg[15] = __expf(-0.5f * node_cost(labels[g1*NN + 15], l2_self, nw));
            sreg[16] = __expf(-0.5f * node_cost(l1_self, labels[g2*NN + 16], nw));
            treg[16] = __expf(-0.5f * node_cost(labels[g1*NN + 16], l2_self, nw));
        } else {
            sreg[15] = ENID; treg[15] = ENID;      // element 32 border
            sreg[16] = 0.f;  treg[16] = 0.f;       // pad
        }

        float cval = 1.0f, rval;
        for (int it = 0; it < ITERS; ++it) {
            float part = 0.f;
            #pragma unroll
            for (int m = 0; m < 17; ++m)
                part += sreg[m] * __int_as_float(
                    __builtin_amdgcn_ds_bpermute(idxr[m], __float_as_int(cval)));
            part += __shfl_xor(part, 32);
            rval = __builtin_amdgcn_rcpf(part);
            if (lane == 63) rval = 1.0f;           // plays the role of r[32]=1
            float part2 = 0.f;
            #pragma unroll
            for (int m = 0; m < 17; ++m)
                part2 += treg[m] * __int_as_float(
                    __builtin_amdgcn_ds_bpermute(idxr[m], __float_as_int(rval)));
            part2 += __shfl_xor(part2, 32);
            cval = __builtin_amdgcn_rcpf(part2);
            if (lane == 63) cval = 1.0f;           // plays the role of c[32]=1
        }
        if (!half) { rr[id] = rval; cc[id] = cval; }
        if (lane == 32) { rr[32] = 1.f; cc[32] = 1.f; }
    } else {
        // ============ waves 1-15: LDS builds (overlap with sinkhorn) ============
        const int t2 = t - 64;                      // 0..959
        if (t2 < 64) ncost_s[t2 >> 3][t2 & 7] = node_cost(t2 >> 3, t2 & 7, nw);
        for (int c0 = t2; c0 < NSQ; c0 += BLK - 64) {
            int i = c0 / NQ, j = c0 - i*NQ;
            int a1 = (i < NN && j < NN) ? A[g1*NN*NN + i*NN + j] : 0;
            int a2 = (i < NN && j < NN) ? A[g2*NN*NN + i*NN + j] : 0;
            A1s[i][j] = (unsigned char)a1;
            A2s[i][j] = (unsigned char)a2;
            float e;
            if (i < NN && j < NN)
                e = __expf(-0.5f * node_cost(labels[g1*NN + i], labels[g2*NN + j], nw));
            else
                e = (i == NN && j == NN) ? 1.f : ENID;
            S[i][j] = e;
        }
    }
    __syncthreads();

    // ---- phase D: materialize V = diag(r) S0 diag(c) in place ----
    for (int c0 = t; c0 < NSQ; c0 += BLK) {
        int i = c0 / NQ, j = c0 - i*NQ;
        S[i][j] *= rr[i] * cc[j];
    }
    __syncthreads();

    // ---- phase E: H[x][i][k] = sum_l f(x, A2[k,l]) V[i,l] ----
    for (int c0 = t; c0 < NSQ; c0 += BLK) {
        int i = c0 / NQ, k = c0 - i*NQ;
        const float* Si = &S[i][0];
        const uint32_t* Aw = (const uint32_t*)&A2s[k][0];
        float p0=0.f, p1=0.f, p2=0.f, p3=0.f, p4=0.f;
        #pragma unroll
        for (int l = 0; l < NQ; ++l) {
            float v = Si[l];
            int a2 = (int)((Aw[l >> 2] >> ((l & 3) * 8)) & 255u);
            p0 += (a2 == 0) ? v : 0.f;
            p1 += (a2 == 1) ? v : 0.f;
            p2 += (a2 == 2) ? v : 0.f;
            p3 += (a2 == 3) ? v : 0.f;
            p4 += (a2 == 4) ? v : 0.f;
        }
        H[0][i][k] = EID * (p1 + p2 + p3 + p4);
        H[1][i][k] = EID * p0 +            e01*p2 + e02*p3 + e03*p4;
        H[2][i][k] = EID * p0 + e01*p1 +            e12*p3 + e13*p4;
        H[3][i][k] = EID * p0 + e02*p1 + e12*p2 +            e23*p4;
        H[4][i][k] = EID * p0 + e03*p1 + e13*p2 + e23*p3;
    }
    __syncthreads();

    // ---- phase F: quad + linear ----
    float qpart = 0.f, lpart = 0.f;
    const float* Hb = &H[0][0][0];
    for (int c0 = t; c0 < NSQ; c0 += BLK) {
        int i = c0 / NQ, j = c0 - i*NQ;
        int x = A1s[i][j];
        const float* Hx = Hb + x*(NQ*NQP) + i*NQP;
        const float* Sj = &S[j][0];
        float dot = 0.f;
        #pragma unroll
        for (int k = 0; k < NQ; ++k) dot += Sj[k] * Hx[k];
        qpart += dot;
        float d;
        if (i < NN && j < NN) d = ncost_s[labels[g1*NN + i]][labels[g2*NN + j]];
        else                  d = (i == NN && j == NN) ? 0.f : NID;
        lpart += d * S[i][j];
    }

    #pragma unroll
    for (int off = 32; off > 0; off >>= 1) {
        qpart += __shfl_down(qpart, off);
        lpart += __shfl_down(lpart, off);
    }
    if ((t & 63) == 0) { wredq[t>>6] = qpart; wredl[t>>6] = lpart; }
    __syncthreads();
    if (t == 0) {
        float q = 0.f, l = 0.f;
        #pragma unroll
        for (int w = 0; w < BLK/64; ++w) { q += wredq[w]; l += wredl[w]; }
        ged_ws[p] = 0.5f * q + l;
    }
}

// out = (ged - min)/(max - min)
__global__ __launch_bounds__(64) void norm_kernel(
    const float* __restrict__ ged, float* __restrict__ out, int P)
{
    int t = threadIdx.x;
    float mn = 1e30f, mx = -1e30f;
    for (int i = t; i < P; i += 64) {
        float g = ged[i];
        mn = fminf(mn, g); mx = fmaxf(mx, g);
    }
    #pragma unroll
    for (int off = 32; off > 0; off >>= 1) {
        mn = fminf(mn, __shfl_xor(mn, off));
        mx = fmaxf(mx, __shfl_xor(mx, off));
    }
    float inv = 1.f / (mx - mn);
    for (int i = t; i < P; i += 64) out[i] = (ged[i] - mn) * inv;
}

extern "C" void kernel_launch(void* const* d_in, const int* in_sizes, int n_in,
                              void* d_out, int out_size, void* d_ws, size_t ws_size,
                              hipStream_t stream) {
    const float* nw     = (const float*)d_in[0];
    const float* ew     = (const float*)d_in[1];
    const int*   A      = (const int*)d_in[2];
    const int*   labels = (const int*)d_in[3];
    const int*   pairs  = (const int*)d_in[4];
    const int P = in_sizes[4] / 2;

    float* ged_ws = (float*)d_ws;

    ged_kernel<<<P, BLK, 0, stream>>>(nw, ew, A, labels, pairs, ged_ws);
    norm_kernel<<<1, 64, 0, stream>>>(ged_ws, (float*)d_out, P);
}

// Round 6
// 21.130 us; speedup vs baseline: 1.1733x; 1.1733x over previous
//
#include <hip/hip_runtime.h>
#include <math.h>
#include <stdint.h>

// Problem constants (fixed by the reference)
constexpr int NQ    = 33;        // N+1
constexpr int NQP   = 34;        // S/S0T leading dim (stride-34 words = 2-way = free)
constexpr int HP    = 36;        // H leading dim (rows 144B -> b128-aligned)
constexpr int NSQ   = NQ * NQ;   // 1089
constexpr int NL    = 8;         // node labels
constexpr int NEL   = 4;         // edge labels
constexpr int NN    = 32;        // N
constexpr int ITERS = 10;        // sinkhorn iterations
constexpr int BLK   = 1024;

// One block per pair. ged[p] -> ged_ws.
__global__ __launch_bounds__(BLK, 1) void ged_kernel(
    const float* __restrict__ nw, const float* __restrict__ ew,
    const int* __restrict__ A, const int* __restrict__ labels,
    const int* __restrict__ pairs, float* __restrict__ ged_ws)
{
    __shared__ __align__(16) float S[NQ][NQP];    // S0, scaled in place to V
    __shared__ __align__(16) float S0T[NQ][NQP];  // S0 transposed
    __shared__ __align__(16) float H[5][NQ][HP];  // H[x][i][k]
    __shared__ unsigned char A1s[NQ][36];
    __shared__ unsigned char A2s[NQ][36];
    __shared__ float ncost[NL][NL];
    __shared__ float encost[NL][NL];              // exp(-0.5*ncost)
    __shared__ float ec[NEL][NEL];
    __shared__ __align__(16) float rr[NQ], cc[NQ], rsum[NQ];
    __shared__ float sNID, sEID, sENID;
    __shared__ int l1s[NN], l2s[NN];
    __shared__ float wredq[16], wredl[16];

    const int t  = threadIdx.x;
    const int p  = blockIdx.x;
    const int g1 = pairs[2*p+0], g2 = pairs[2*p+1];

    // ---- phase A: tables (wave 0 lanes), labels, adjacency ----
    if (t < 28) {                            // node substitution costs
        int i = (t>=27)?6 : (t>=25)?5 : (t>=22)?4 : (t>=18)?3 : (t>=13)?2 : (t>=7)?1 : 0;
        int off = (i==0)?0 : (i==1)?7 : (i==2)?13 : (i==3)?18 : (i==4)?22 : (i==5)?25 : 27;
        int j = t - off + i + 1;
        float v = fmaxf(nw[t], 0.f);
        ncost[i][j] = v; ncost[j][i] = v;
        float e = __expf(-0.5f * v);
        encost[i][j] = e; encost[j][i] = e;
    } else if (t == 28) {
        float v = fmaxf(nw[28], 0.f);
        sNID = v; sENID = __expf(-0.5f * v);
    } else if (t >= 32 && t < 38) {          // edge substitution costs
        int q = t - 32;
        // triu_indices(4,k=1): (0,1)(0,2)(0,3)(1,2)(1,3)(2,3)
        int ei = (q<3)?0 : (q<5)?1 : 2;
        int ej = (q<3)?q+1 : (q<5)?q-1 : 3;
        float v = fmaxf(ew[q], 0.f);
        ec[ei][ej] = v; ec[ej][ei] = v;
    } else if (t == 38) {
        sEID = fmaxf(ew[6], 0.f);
    } else if (t >= 40 && t < 48) {          // diagonals
        int q = t - 40;
        ncost[q][q] = 0.f; encost[q][q] = 1.f;
    } else if (t >= 48 && t < 52) {
        int q = t - 48;
        ec[q][q] = 0.f;
    } else if (t >= 56 && t < 56 + NQ) {
        cc[t - 56] = 1.f;                    // sinkhorn col-scale init
    }
    if (t >= 64  && t < 64 + NN)  l1s[t - 64]  = labels[g1*NN + (t - 64)];
    if (t >= 96  && t < 96 + NN)  l2s[t - 96]  = labels[g2*NN + (t - 96)];
    for (int c0 = t; c0 < NSQ; c0 += BLK) {
        int i = c0 / NQ, j = c0 - i*NQ;
        int a1 = (i < NN && j < NN) ? A[g1*NN*NN + i*NN + j] : 0;
        int a2 = (i < NN && j < NN) ? A[g2*NN*NN + i*NN + j] : 0;
        A1s[i][j] = (unsigned char)a1;
        A2s[i][j] = (unsigned char)a2;
    }
    __syncthreads();

    const float NID = sNID, EID = sEID, ENID = sENID;
    const float e01 = ec[0][1], e02 = ec[0][2], e03 = ec[0][3];
    const float e12 = ec[1][2], e13 = ec[1][3], e23 = ec[2][3];

    // ---- phase B: S0 (and transpose) from encost table ----
    for (int c0 = t; c0 < NSQ; c0 += BLK) {
        int i = c0 / NQ, j = c0 - i*NQ;
        float e = (i < NN && j < NN) ? encost[l1s[i]][l2s[j]]
                                     : ((i == NN && j == NN) ? 1.f : ENID);
        S[i][j]   = e;
        S0T[j][i] = e;
    }
    __syncthreads();

    // ---- phase C: sinkhorn on wave-0 lanes 0..32, scaling form ----
    // r[i] = 1/sum_j S0[i][j]*c[j];  c[j] = 1/sum_i S0[i][j]*r[i]; idx 32 -> 1.
    // 4-way partial sums break the serial FMA chain.
    if (t < NQ) {
        const float* Srow = &S[t][0];
        const float* Trow = &S0T[t][0];
        float rval = 1.f;
        for (int it = 0; it < ITERS; ++it) {
            float a0=0.f, a1=0.f, a2=0.f, a3=0.f;
            #pragma unroll
            for (int j = 0; j < 32; j += 4) {
                a0 += Srow[j+0]*cc[j+0]; a1 += Srow[j+1]*cc[j+1];
                a2 += Srow[j+2]*cc[j+2]; a3 += Srow[j+3]*cc[j+3];
            }
            float s = ((a0+a1)+(a2+a3)) + Srow[32]*cc[32];
            rval = (t == NQ-1) ? 1.f : __builtin_amdgcn_rcpf(s);
            rr[t] = rval;
            float b0=0.f, b1=0.f, b2=0.f, b3=0.f;
            #pragma unroll
            for (int j = 0; j < 32; j += 4) {
                b0 += Trow[j+0]*rr[j+0]; b1 += Trow[j+1]*rr[j+1];
                b2 += Trow[j+2]*rr[j+2]; b3 += Trow[j+3]*rr[j+3];
            }
            float s2 = ((b0+b1)+(b2+b3)) + Trow[32]*rr[32];
            cc[t] = (t == NQ-1) ? 1.f : __builtin_amdgcn_rcpf(s2);
        }
        // rowsum of final V: rsum[i] = rr[i] * sum_j S0[i][j]*cc_final[j]
        float a0=0.f, a1=0.f, a2=0.f, a3=0.f;
        #pragma unroll
        for (int j = 0; j < 32; j += 4) {
            a0 += Srow[j+0]*cc[j+0]; a1 += Srow[j+1]*cc[j+1];
            a2 += Srow[j+2]*cc[j+2]; a3 += Srow[j+3]*cc[j+3];
        }
        float sf = ((a0+a1)+(a2+a3)) + Srow[32]*cc[32];
        rsum[t] = rval * sf;
    }
    __syncthreads();

    // ---- phase D: materialize V = diag(r) S0 diag(c) in place ----
    for (int c0 = t; c0 < NSQ; c0 += BLK) {
        int i = c0 / NQ, j = c0 - i*NQ;
        S[i][j] *= rr[i] * cc[j];
    }
    __syncthreads();

    // ---- phase E: H[x][i][k]; p0 recovered from rsum (no selects for y=0) ----
    for (int c0 = t; c0 < NSQ; c0 += BLK) {
        int i = c0 / NQ, k = c0 - i*NQ;
        const float* Si = &S[i][0];
        const uint32_t* Aw = (const uint32_t*)&A2s[k][0];
        float p1=0.f, p2=0.f, p3=0.f, p4=0.f;
        #pragma unroll
        for (int l = 0; l < NQ; ++l) {
            float v = Si[l];
            int a2v = (int)((Aw[l >> 2] >> ((l & 3) * 8)) & 255u);
            p1 += (a2v == 1) ? v : 0.f;
            p2 += (a2v == 2) ? v : 0.f;
            p3 += (a2v == 3) ? v : 0.f;
            p4 += (a2v == 4) ? v : 0.f;
        }
        float t4 = (p1 + p2) + (p3 + p4);
        float p0 = rsum[i] - t4;
        H[0][i][k] = EID * t4;
        H[1][i][k] = EID * p0 +            e01*p2 + e02*p3 + e03*p4;
        H[2][i][k] = EID * p0 + e01*p1 +            e12*p3 + e13*p4;
        H[3][i][k] = EID * p0 + e02*p1 + e12*p2 +            e23*p4;
        H[4][i][k] = EID * p0 + e03*p1 + e13*p2 + e23*p3;
    }
    __syncthreads();

    // ---- phase F: quad + linear, j-tiled (thread = (j, group of 3 i's)) ----
    // V row j cached in registers once, reused for 3 dots.
    float qpart = 0.f, lpart = 0.f;
    if (t < 363) {
        const int j  = t / 11;
        const int ig = t - j*11;
        float Vr[34];
        const float2* Sj2 = (const float2*)&S[j][0];
        #pragma unroll
        for (int m = 0; m < 17; ++m) {
            float2 w = Sj2[m];
            Vr[2*m] = w.x; Vr[2*m+1] = w.y;
        }
        #pragma unroll
        for (int ii = 0; ii < 3; ++ii) {
            const int i = ig*3 + ii;
            const int x = A1s[i][j];
            const float* Hx = &H[x][i][0];
            float d0=0.f, d1=0.f, d2=0.f, d3=0.f;
            #pragma unroll
            for (int k = 0; k < 32; k += 4) {
                d0 += Vr[k+0]*Hx[k+0]; d1 += Vr[k+1]*Hx[k+1];
                d2 += Vr[k+2]*Hx[k+2]; d3 += Vr[k+3]*Hx[k+3];
            }
            qpart += ((d0+d1)+(d2+d3)) + Vr[32]*Hx[32];
            float d;
            if (i < NN && j < NN) d = ncost[l1s[i]][l2s[j]];
            else                  d = (i == NN && j == NN) ? 0.f : NID;
            lpart += d * S[i][j];
        }
    }

    #pragma unroll
    for (int off = 32; off > 0; off >>= 1) {
        qpart += __shfl_down(qpart, off);
        lpart += __shfl_down(lpart, off);
    }
    if ((t & 63) == 0) { wredq[t>>6] = qpart; wredl[t>>6] = lpart; }
    __syncthreads();
    if (t < 16) {
        float q = wredq[t], l = wredl[t];
        q += __shfl_down(q, 8); l += __shfl_down(l, 8);
        q += __shfl_down(q, 4); l += __shfl_down(l, 4);
        q += __shfl_down(q, 2); l += __shfl_down(l, 2);
        q += __shfl_down(q, 1); l += __shfl_down(l, 1);
        if (t == 0) ged_ws[p] = 0.5f * q + l;
    }
}

// out = (ged - min)/(max - min)
__global__ __launch_bounds__(64) void norm_kernel(
    const float* __restrict__ ged, float* __restrict__ out, int P)
{
    int t = threadIdx.x;
    float mn = 1e30f, mx = -1e30f;
    for (int i = t; i < P; i += 64) {
        float g = ged[i];
        mn = fminf(mn, g); mx = fmaxf(mx, g);
    }
    #pragma unroll
    for (int off = 32; off > 0; off >>= 1) {
        mn = fminf(mn, __shfl_xor(mn, off));
        mx = fmaxf(mx, __shfl_xor(mx, off));
    }
    float inv = 1.f / (mx - mn);
    for (int i = t; i < P; i += 64) out[i] = (ged[i] - mn) * inv;
}

extern "C" void kernel_launch(void* const* d_in, const int* in_sizes, int n_in,
                              void* d_out, int out_size, void* d_ws, size_t ws_size,
                              hipStream_t stream) {
    const float* nw     = (const float*)d_in[0];
    const float* ew     = (const float*)d_in[1];
    const int*   A      = (const int*)d_in[2];
    const int*   labels = (const int*)d_in[3];
    const int*   pairs  = (const int*)d_in[4];
    const int P = in_sizes[4] / 2;

    float* ged_ws = (float*)d_ws;

    ged_kernel<<<P, BLK, 0, stream>>>(nw, ew, A, labels, pairs, ged_ws);
    norm_kernel<<<1, 64, 0, stream>>>(ged_ws, (float*)d_out, P);
}